// Round 2
// baseline (163.540 us; speedup 1.0000x reference)
//
#include <hip/hip_runtime.h>

typedef float f32x4 __attribute__((ext_vector_type(4)));
typedef __bf16 bf16x8 __attribute__((ext_vector_type(8)));

#define H_DIM 4096
#define I_DIM 11008
#define ITERS1_TOTAL (H_DIM / 32)   // 128
#define ITERS2_TOTAL (I_DIM / 32)   // 344

// 2:4 prune of one contiguous group of 4 (matches jnp.argsort stable-tie
// semantics: keep element i iff #{j: |wj|<|wi| or (|wj|==|wi| and j<i)} >= 2)
__device__ __forceinline__ f32x4 prune4(f32x4 w) {
    float a0 = fabsf(w[0]), a1 = fabsf(w[1]), a2 = fabsf(w[2]), a3 = fabsf(w[3]);
    int r0 = (int)(a1 < a0) + (int)(a2 < a0) + (int)(a3 < a0);
    int r1 = (int)(a0 <= a1) + (int)(a2 < a1) + (int)(a3 < a1);
    int r2 = (int)(a0 <= a2) + (int)(a1 <= a2) + (int)(a3 < a2);
    int r3 = (int)(a0 <= a3) + (int)(a1 <= a3) + (int)(a2 <= a3);
    w[0] = (r0 >= 2) ? w[0] : 0.0f;
    w[1] = (r1 >= 2) ? w[1] : 0.0f;
    w[2] = (r2 >= 2) ? w[2] : 0.0f;
    w[3] = (r3 >= 2) ? w[3] : 0.0f;
    return w;
}

__device__ __forceinline__ bf16x8 cvt8(f32x4 a, f32x4 b) {
    bf16x8 r;
    r[0] = (__bf16)a[0]; r[1] = (__bf16)a[1];
    r[2] = (__bf16)a[2]; r[3] = (__bf16)a[3];
    r[4] = (__bf16)b[0]; r[5] = (__bf16)b[1];
    r[6] = (__bf16)b[2]; r[7] = (__bf16)b[3];
    return r;
}

// split s of nsplit over `total` 32-wide k-iters: first r splits get q+1
__device__ __forceinline__ void ksplit(int s, int nsplit, int total,
                                       int& kbeg, int& iters) {
    int q = total / nsplit, r = total % nsplit;
    iters = q + (s < r ? 1 : 0);
    kbeg = 32 * (s * q + (s < r ? s : r));
}

__global__ __launch_bounds__(256) void k_cvt_x(const float* __restrict__ x,
                                               __bf16* __restrict__ xb) {
    int i = (blockIdx.x * 256 + threadIdx.x) * 4;
    f32x4 v = *(const f32x4*)(x + i);
    xb[i + 0] = (__bf16)v[0]; xb[i + 1] = (__bf16)v[1];
    xb[i + 2] = (__bf16)v[2]; xb[i + 3] = (__bf16)v[3];
}

// gate+up fused: wave = 16 output cols x 32 tokens; k-split via blockIdx.y.
// 1-deep software pipeline: iter it+1's loads issue before iter it's compute.
__global__ __launch_bounds__(256) void k_gateup(
        const float* __restrict__ GW, const float* __restrict__ UW,
        const __bf16* __restrict__ XB,
        float* __restrict__ gpart, float* __restrict__ upart, int nsplit) {
    const int lane = threadIdx.x & 63;
    const int wv   = threadIdx.x >> 6;
    const int i0   = (blockIdx.x * 4 + wv) * 16;   // 172 blocks * 4 * 16 = 11008
    const int s    = blockIdx.y;
    int kbeg, iters;
    ksplit(s, nsplit, ITERS1_TOTAL, kbeg, iters);
    const int lrow = lane & 15;
    const int lk   = (lane >> 4) << 3;

    const float*  gp  = GW + (size_t)(i0 + lrow) * H_DIM + kbeg + lk;
    const float*  up  = UW + (size_t)(i0 + lrow) * H_DIM + kbeg + lk;
    const __bf16* xp0 = XB + (size_t)lrow * H_DIM + kbeg + lk;
    const __bf16* xp1 = xp0 + (size_t)16 * H_DIM;

    f32x4 aG0 = {0,0,0,0}, aG1 = {0,0,0,0}, aU0 = {0,0,0,0}, aU1 = {0,0,0,0};

    // prologue: load iter 0
    f32x4 cg0 = *(const f32x4*)(gp);     f32x4 cg1 = *(const f32x4*)(gp + 4);
    f32x4 cu0 = *(const f32x4*)(up);     f32x4 cu1 = *(const f32x4*)(up + 4);
    bf16x8 ca0 = *(const bf16x8*)(xp0);  bf16x8 ca1 = *(const bf16x8*)(xp1);

    #pragma unroll 2
    for (int it = 0; it < iters - 1; ++it) {
        const int ko = (it + 1) * 32;
        f32x4 ng0 = *(const f32x4*)(gp + ko);
        f32x4 ng1 = *(const f32x4*)(gp + ko + 4);
        f32x4 nu0 = *(const f32x4*)(up + ko);
        f32x4 nu1 = *(const f32x4*)(up + ko + 4);
        bf16x8 na0 = *(const bf16x8*)(xp0 + ko);
        bf16x8 na1 = *(const bf16x8*)(xp1 + ko);

        bf16x8 bg = cvt8(prune4(cg0), prune4(cg1));
        bf16x8 bu = cvt8(prune4(cu0), prune4(cu1));
        aG0 = __builtin_amdgcn_mfma_f32_16x16x32_bf16(ca0, bg, aG0, 0, 0, 0);
        aG1 = __builtin_amdgcn_mfma_f32_16x16x32_bf16(ca1, bg, aG1, 0, 0, 0);
        aU0 = __builtin_amdgcn_mfma_f32_16x16x32_bf16(ca0, bu, aU0, 0, 0, 0);
        aU1 = __builtin_amdgcn_mfma_f32_16x16x32_bf16(ca1, bu, aU1, 0, 0, 0);

        cg0 = ng0; cg1 = ng1; cu0 = nu0; cu1 = nu1; ca0 = na0; ca1 = na1;
    }
    {   // epilogue
        bf16x8 bg = cvt8(prune4(cg0), prune4(cg1));
        bf16x8 bu = cvt8(prune4(cu0), prune4(cu1));
        aG0 = __builtin_amdgcn_mfma_f32_16x16x32_bf16(ca0, bg, aG0, 0, 0, 0);
        aG1 = __builtin_amdgcn_mfma_f32_16x16x32_bf16(ca1, bg, aG1, 0, 0, 0);
        aU0 = __builtin_amdgcn_mfma_f32_16x16x32_bf16(ca0, bu, aU0, 0, 0, 0);
        aU1 = __builtin_amdgcn_mfma_f32_16x16x32_bf16(ca1, bu, aU1, 0, 0, 0);
    }

    const int col = i0 + lrow;
    const int t0  = (lane >> 4) * 4;          // C/D: col=lane&15, row=(lane>>4)*4+r
    const size_t srow = (size_t)s * 32;
    #pragma unroll
    for (int r = 0; r < 4; ++r) {
        size_t iA = (srow + t0 + r) * I_DIM + col;
        size_t iB = (srow + t0 + 16 + r) * I_DIM + col;
        gpart[iA] = aG0[r];  gpart[iB] = aG1[r];
        upart[iA] = aU0[r];  upart[iB] = aU1[r];
    }
}

__global__ __launch_bounds__(256) void k_hidden(
        const float* __restrict__ gpart, const float* __restrict__ upart,
        const float* __restrict__ gb, const float* __restrict__ ub,
        __bf16* __restrict__ hb, int nsplit) {
    const int i = blockIdx.x * 256 + threadIdx.x;  // 43*256 = 11008
    const int t = blockIdx.y;
    float g = gb[i], u = ub[i];
    for (int s = 0; s < nsplit; ++s) {
        g += gpart[(size_t)(s * 32 + t) * I_DIM + i];
        u += upart[(size_t)(s * 32 + t) * I_DIM + i];
    }
    float h = g / (1.0f + __expf(-g)) * u;   // silu(g)*u
    hb[(size_t)t * I_DIM + i] = (__bf16)h;
}

__global__ __launch_bounds__(256) void k_down(
        const float* __restrict__ DW, const __bf16* __restrict__ HB,
        float* __restrict__ opart, int nsplit) {
    const int lane = threadIdx.x & 63;
    const int wv   = threadIdx.x >> 6;
    const int o0   = (blockIdx.x * 4 + wv) * 16;   // 64 blocks * 4 * 16 = 4096
    const int s    = blockIdx.y;
    int kbeg, iters;
    ksplit(s, nsplit, ITERS2_TOTAL, kbeg, iters);
    const int lrow = lane & 15;
    const int lk   = (lane >> 4) << 3;

    const float*  dp  = DW + (size_t)(o0 + lrow) * I_DIM + kbeg + lk;
    const __bf16* hp0 = HB + (size_t)lrow * I_DIM + kbeg + lk;
    const __bf16* hp1 = hp0 + (size_t)16 * I_DIM;

    f32x4 acc0 = {0,0,0,0}, acc1 = {0,0,0,0};

    f32x4 cd0 = *(const f32x4*)(dp);     f32x4 cd1 = *(const f32x4*)(dp + 4);
    bf16x8 ch0 = *(const bf16x8*)(hp0);  bf16x8 ch1 = *(const bf16x8*)(hp1);

    #pragma unroll 2
    for (int it = 0; it < iters - 1; ++it) {
        const int ko = (it + 1) * 32;
        f32x4 nd0 = *(const f32x4*)(dp + ko);
        f32x4 nd1 = *(const f32x4*)(dp + ko + 4);
        bf16x8 nh0 = *(const bf16x8*)(hp0 + ko);
        bf16x8 nh1 = *(const bf16x8*)(hp1 + ko);

        bf16x8 bw = cvt8(cd0, cd1);
        acc0 = __builtin_amdgcn_mfma_f32_16x16x32_bf16(ch0, bw, acc0, 0, 0, 0);
        acc1 = __builtin_amdgcn_mfma_f32_16x16x32_bf16(ch1, bw, acc1, 0, 0, 0);

        cd0 = nd0; cd1 = nd1; ch0 = nh0; ch1 = nh1;
    }
    {
        bf16x8 bw = cvt8(cd0, cd1);
        acc0 = __builtin_amdgcn_mfma_f32_16x16x32_bf16(ch0, bw, acc0, 0, 0, 0);
        acc1 = __builtin_amdgcn_mfma_f32_16x16x32_bf16(ch1, bw, acc1, 0, 0, 0);
    }

    const int col = o0 + lrow;
    const int t0  = (lane >> 4) * 4;
    const size_t srow = (size_t)s * 32;
    #pragma unroll
    for (int r = 0; r < 4; ++r) {
        opart[(srow + t0 + r) * H_DIM + col]      = acc0[r];
        opart[(srow + t0 + 16 + r) * H_DIM + col] = acc1[r];
    }
}

__global__ __launch_bounds__(256) void k_out(
        const float* __restrict__ opart, const float* __restrict__ db,
        float* __restrict__ out, int nsplit) {
    const int o = blockIdx.x * 256 + threadIdx.x;  // 16*256 = 4096
    const int t = blockIdx.y;
    float v = db[o];
    for (int s = 0; s < nsplit; ++s)
        v += opart[(size_t)(s * 32 + t) * H_DIM + o];
    out[(size_t)t * H_DIM + o] = v;
}

extern "C" void kernel_launch(void* const* d_in, const int* in_sizes, int n_in,
                              void* d_out, int out_size, void* d_ws, size_t ws_size,
                              hipStream_t stream) {
    const float* x  = (const float*)d_in[0];
    const float* gw = (const float*)d_in[1];
    const float* uw = (const float*)d_in[2];
    const float* dw = (const float*)d_in[3];
    const float* gb = (const float*)d_in[4];
    const float* ub = (const float*)d_in[5];
    const float* db = (const float*)d_in[6];
    float* out = (float*)d_out;

    const size_t XB_BYTES = (size_t)32 * H_DIM * 2;          // 256 KiB
    const size_t HB_BYTES = (size_t)32 * I_DIM * 2;          // 688 KiB
    const size_t GP_UNIT  = (size_t)32 * I_DIM * 4;          // 1.38 MiB per split
    const size_t OP_UNIT  = (size_t)32 * H_DIM * 4;          // 0.5 MiB per split

    // pick largest split config that fits ws (deterministic: ws_size is fixed)
    int ns1 = 16, ns2 = 16;
    while (ns1 > 4 &&
           XB_BYTES + HB_BYTES + 2 * GP_UNIT * ns1 + OP_UNIT * ns2 > ws_size)
        ns1 >>= 1;
    while (ns2 > 8 &&
           XB_BYTES + HB_BYTES + 2 * GP_UNIT * ns1 + OP_UNIT * ns2 > ws_size)
        ns2 >>= 1;

    char* ws = (char*)d_ws;
    __bf16* xb    = (__bf16*)(ws);
    __bf16* hb    = (__bf16*)(ws + XB_BYTES);
    float*  gpart = (float*)(ws + XB_BYTES + HB_BYTES);
    float*  upart = (float*)(ws + XB_BYTES + HB_BYTES + GP_UNIT * ns1);
    float*  opart = (float*)(ws + XB_BYTES + HB_BYTES + 2 * GP_UNIT * ns1);

    k_cvt_x <<<dim3(128),       dim3(256), 0, stream>>>(x, xb);
    k_gateup<<<dim3(172, ns1),  dim3(256), 0, stream>>>(gw, uw, xb, gpart, upart, ns1);
    k_hidden<<<dim3(43, 32),    dim3(256), 0, stream>>>(gpart, upart, gb, ub, hb, ns1);
    k_down  <<<dim3(64, ns2),   dim3(256), 0, stream>>>(dw, hb, opart, ns2);
    k_out   <<<dim3(16, 32),    dim3(256), 0, stream>>>(opart, db, out, ns2);
}